// Round 1
// 423.179 us; speedup vs baseline: 1.0099x; 1.0099x over previous
//
#include <hip/hip_runtime.h>
#include <math.h>

// Householder reflection + bias, fused single kernel.
//   out[i,:] = x[i,:] - 2*(x[i,:]·vhat)*vhat + bias,  vhat = v/(||v||+1e-14)
// Rewritten: c_i = 2*inv^2*(x_i·v), inv = 1/(sqrt(v·v)+eps)
//            out[i,j] = fma(-c_i, v[j], x[i,j]) + bias[j]
//
// One row per 256-thread block. Each thread owns 16 columns (4 float4s at
// stride 256 float4s -> coalesced 1KB/instr) held in registers across the
// reduction barrier so x is fetched from HBM exactly once. v·v is reduced
// alongside x·v per block (v loads are needed for the update anyway; v is
// L2-resident), so no separate norm kernel / workspace is needed.
//
// This revision: x loads and out stores are NONTEMPORAL (streaming, zero
// reuse -> don't allocate in L1/L2), while v and bias stay on the cached
// path (32 KiB total, re-read by every resident block -> must stay L2-hot).
// Rationale: 512 MiB of streaming traffic thrashing L2 competes with the
// only cache-resident data we have; nt frees the cache for v/bias and
// typically buys a few % of effective HBM BW on pure streams.

typedef float v4f __attribute__((ext_vector_type(4)));

__global__ __launch_bounds__(256) void householder_kernel(
    const float* __restrict__ x,
    const float* __restrict__ v,
    const float* __restrict__ bias,
    float* __restrict__ out,
    int n)  // n == 4096, block covers n/4 = 1024 float4s with 256 threads
{
    const int row = blockIdx.x;
    const int tid = threadIdx.x;
    const v4f* __restrict__ xr = (const v4f*)(x + (size_t)row * n);
    const v4f* __restrict__ vp = (const v4f*)v;
    const v4f* __restrict__ bp = (const v4f*)bias;
    v4f* __restrict__ outr = (v4f*)(out + (size_t)row * n);

    v4f xreg[4];
    v4f vreg[4];
    float svv = 0.0f;
    float sxv = 0.0f;

    #pragma unroll
    for (int k = 0; k < 4; ++k) {
        const int idx = tid + (k << 8);    // tid + k*256, idx < n/4
        v4f xx = __builtin_nontemporal_load(&xr[idx]);  // streaming: nt
        v4f vv = vp[idx];                                // reused: cached
        xreg[k] = xx;
        vreg[k] = vv;
        svv = fmaf(vv.x, vv.x, svv);
        svv = fmaf(vv.y, vv.y, svv);
        svv = fmaf(vv.z, vv.z, svv);
        svv = fmaf(vv.w, vv.w, svv);
        sxv = fmaf(xx.x, vv.x, sxv);
        sxv = fmaf(xx.y, vv.y, sxv);
        sxv = fmaf(xx.z, vv.z, sxv);
        sxv = fmaf(xx.w, vv.w, sxv);
    }

    // Wave (64-lane) down-shuffle reduce of both partials.
    #pragma unroll
    for (int off = 32; off > 0; off >>= 1) {
        svv += __shfl_down(svv, off, 64);
        sxv += __shfl_down(sxv, off, 64);
    }

    // Cross-wave (4 waves) combine via LDS, broadcast to all threads.
    __shared__ float red[8];
    const int wid = tid >> 6;
    if ((tid & 63) == 0) {
        red[wid] = svv;
        red[4 + wid] = sxv;
    }
    __syncthreads();
    svv = red[0] + red[1] + red[2] + red[3];
    sxv = red[4] + red[5] + red[6] + red[7];

    const float inv = 1.0f / (sqrtf(svv) + 1e-14f);
    const float c = 2.0f * inv * inv * sxv;

    #pragma unroll
    for (int k = 0; k < 4; ++k) {
        const int idx = tid + (k << 8);
        const v4f bb = bp[idx];            // L2-hot: cached path
        const v4f xx = xreg[k];
        const v4f vv = vreg[k];
        v4f o;
        o.x = fmaf(-c, vv.x, xx.x) + bb.x;
        o.y = fmaf(-c, vv.y, xx.y) + bb.y;
        o.z = fmaf(-c, vv.z, xx.z) + bb.z;
        o.w = fmaf(-c, vv.w, xx.w) + bb.w;
        __builtin_nontemporal_store(o, &outr[idx]);     // streaming: nt
    }
}

extern "C" void kernel_launch(void* const* d_in, const int* in_sizes, int n_in,
                              void* d_out, int out_size, void* d_ws, size_t ws_size,
                              hipStream_t stream) {
    (void)n_in; (void)d_ws; (void)ws_size;
    const float* x    = (const float*)d_in[0];
    const float* v    = (const float*)d_in[1];
    const float* bias = (const float*)d_in[2];
    float* out = (float*)d_out;

    const int n = in_sizes[1];             // 4096 (vector is n x 1)
    const int batch = in_sizes[0] / n;     // 16384

    householder_kernel<<<batch, 256, 0, stream>>>(x, v, bias, out, n);
}